// Round 1
// baseline (158.336 us; speedup 1.0000x reference)
//
#include <hip/hip_runtime.h>
#include <hip/hip_bf16.h>

// Problem constants
#define BB 8
#define HH 640
#define WW 640
#define HWN (HH * WW)          // 409600 pixels per batch
#define NUM_INST 16
#define BLOCKS_PER_BATCH 200
#define THREADS 256

// Workspace layout (floats):
// [0..127]    s1 per segment (b*16+k)
// [128..255]  s2 per segment
// [256..383]  cnt per segment
// [384..391]  posSum per batch
// [392..399]  negSum per batch
// [400..407]  orSum per batch
// [408..415]  posCnt per batch
#define WS_FLOATS 416

__device__ __forceinline__ void process_pixel(
    float p1, float p2, float c, float t, int k,
    float& accPos, float& accNeg, float& accOr, float& accCnt,
    float* lds_s1, float* lds_s2, float* lds_cnt)
{
    float andp = p1 * p2;
    // BCE(and_preds, overlap); overlap is exactly 0.0 or 1.0
    float lp   = fmaxf(__logf(andp), -100.0f);
    float l1p  = fmaxf(__logf(1.0f - andp), -100.0f);
    float bce_and = (t != 0.0f) ? -lp : -l1p;
    accPos += (c != 0.0f) ? bce_and : 0.0f;
    accNeg += (c == 0.0f) ? bce_and : 0.0f;
    accCnt += c;
    // BCE(max(p1,p2), conf)
    float mx   = fmaxf(p1, p2);
    float lpo  = fmaxf(__logf(mx), -100.0f);
    float l1po = fmaxf(__logf(1.0f - mx), -100.0f);
    accOr += (c != 0.0f) ? -lpo : -l1po;
    // instance term
    float ao  = (t != 0.0f) ? andp : 0.0f;   // and_preds * overlap
    float op1 = fmaxf(p1, ao);
    float op2 = fmaxf(p2, ao);
    float e1 = (op1 - 1.0f) * (op1 - 1.0f);
    float e2 = (op2 - 1.0f) * (op2 - 1.0f);
    atomicAdd(&lds_s1[k], e1);
    atomicAdd(&lds_s2[k], e2);
    atomicAdd(&lds_cnt[k], 1.0f);
}

__global__ __launch_bounds__(THREADS) void overlap_main_kernel(
    const float* __restrict__ preds, const float* __restrict__ conf,
    const int* __restrict__ inst, const float* __restrict__ overlap,
    float* __restrict__ ws)
{
    __shared__ float lds_s1[NUM_INST];
    __shared__ float lds_s2[NUM_INST];
    __shared__ float lds_cnt[NUM_INST];
    __shared__ float wred[4][4];  // [wave][scalar]

    const int b   = blockIdx.y;
    const int tid = threadIdx.x;

    if (tid < NUM_INST) {
        lds_s1[tid] = 0.0f; lds_s2[tid] = 0.0f; lds_cnt[tid] = 0.0f;
    }
    __syncthreads();

    const float4* p1v = (const float4*)(preds + (size_t)b * 2 * HWN);
    const float4* p2v = (const float4*)(preds + (size_t)b * 2 * HWN + HWN);
    const float4* cv  = (const float4*)(conf   + (size_t)b * HWN);
    const float4* tv  = (const float4*)(overlap + (size_t)b * HWN);
    const int4*   kv  = (const int4*)(inst     + (size_t)b * HWN);

    float accPos = 0.0f, accNeg = 0.0f, accOr = 0.0f, accCnt = 0.0f;

    const int nvec   = HWN / 4;
    const int stride = gridDim.x * blockDim.x;
    for (int i = blockIdx.x * blockDim.x + tid; i < nvec; i += stride) {
        float4 a  = p1v[i];
        float4 bq = p2v[i];
        float4 c4 = cv[i];
        float4 t4 = tv[i];
        int4   k4 = kv[i];
        process_pixel(a.x, bq.x, c4.x, t4.x, k4.x, accPos, accNeg, accOr, accCnt, lds_s1, lds_s2, lds_cnt);
        process_pixel(a.y, bq.y, c4.y, t4.y, k4.y, accPos, accNeg, accOr, accCnt, lds_s1, lds_s2, lds_cnt);
        process_pixel(a.z, bq.z, c4.z, t4.z, k4.z, accPos, accNeg, accOr, accCnt, lds_s1, lds_s2, lds_cnt);
        process_pixel(a.w, bq.w, c4.w, t4.w, k4.w, accPos, accNeg, accOr, accCnt, lds_s1, lds_s2, lds_cnt);
    }

    // wave-level reduce of the 4 scalar accumulators (wave = 64 lanes)
    #pragma unroll
    for (int off = 32; off > 0; off >>= 1) {
        accPos += __shfl_down(accPos, off);
        accNeg += __shfl_down(accNeg, off);
        accOr  += __shfl_down(accOr,  off);
        accCnt += __shfl_down(accCnt, off);
    }
    const int wave = tid >> 6;
    const int lane = tid & 63;
    if (lane == 0) {
        wred[wave][0] = accPos;
        wred[wave][1] = accNeg;
        wred[wave][2] = accOr;
        wred[wave][3] = accCnt;
    }
    __syncthreads();  // also makes all LDS segment atomics visible

    if (tid == 0) {
        float sPos = wred[0][0] + wred[1][0] + wred[2][0] + wred[3][0];
        float sNeg = wred[0][1] + wred[1][1] + wred[2][1] + wred[3][1];
        float sOr  = wred[0][2] + wred[1][2] + wred[2][2] + wred[3][2];
        float sCnt = wred[0][3] + wred[1][3] + wred[2][3] + wred[3][3];
        atomicAdd(&ws[384 + b], sPos);
        atomicAdd(&ws[392 + b], sNeg);
        atomicAdd(&ws[400 + b], sOr);
        atomicAdd(&ws[408 + b], sCnt);
    }
    if (tid < NUM_INST) {
        atomicAdd(&ws[      b * NUM_INST + tid], lds_s1[tid]);
        atomicAdd(&ws[128 + b * NUM_INST + tid], lds_s2[tid]);
        atomicAdd(&ws[256 + b * NUM_INST + tid], lds_cnt[tid]);
    }
}

__global__ __launch_bounds__(128) void overlap_finalize_kernel(
    const float* __restrict__ ws, float* __restrict__ out)
{
    __shared__ float perkey[128];
    __shared__ float pres[128];
    const int t = threadIdx.x;
    if (t < 128) {
        float cnt = ws[256 + t];
        float s1  = ws[t];
        float s2  = ws[128 + t];
        bool present = cnt > 0.0f;
        float sc = present ? cnt : 1.0f;
        float d1 = s1 / sc;
        float d2 = s2 / sc;
        perkey[t] = present ? (1.0f - fabsf(d1 - d2)) : 0.0f;
        pres[t]   = present ? 1.0f : 0.0f;
    }
    __syncthreads();
    if (t == 0) {
        float instLoss = 0.0f;
        for (int b = 0; b < BB; b++) {
            float s = 0.0f, nk = 0.0f;
            for (int k = 0; k < NUM_INST; k++) {
                s  += perkey[b * NUM_INST + k];
                nk += pres[b * NUM_INST + k];
            }
            instLoss += s / nk;
        }
        instLoss /= (float)BB;
        float posS = 0.0f, negS = 0.0f, orS = 0.0f, posC = 0.0f;
        for (int b = 0; b < BB; b++) {
            posS += ws[384 + b];
            negS += ws[392 + b];
            orS  += ws[400 + b];
            posC += ws[408 + b];
        }
        const float N = (float)BB * (float)HWN;
        float andLoss = posS / posC + negS / (N - posC);
        float orLoss  = orS / N;
        out[0] = 0.5f * andLoss + 0.25f * orLoss + 0.25f * instLoss;
    }
}

extern "C" void kernel_launch(void* const* d_in, const int* in_sizes, int n_in,
                              void* d_out, int out_size, void* d_ws, size_t ws_size,
                              hipStream_t stream) {
    const float* preds   = (const float*)d_in[0];
    const float* conf    = (const float*)d_in[1];
    const int*   inst    = (const int*)d_in[2];
    const float* overlap = (const float*)d_in[3];
    // d_in[4] (inds) is unused by the reference computation.
    float* ws  = (float*)d_ws;
    float* out = (float*)d_out;

    hipMemsetAsync(ws, 0, WS_FLOATS * sizeof(float), stream);
    dim3 grid(BLOCKS_PER_BATCH, BB);
    overlap_main_kernel<<<grid, THREADS, 0, stream>>>(preds, conf, inst, overlap, ws);
    overlap_finalize_kernel<<<1, 128, 0, stream>>>(ws, out);
}

// Round 2
// 114.864 us; speedup vs baseline: 1.3785x; 1.3785x over previous
//
#include <hip/hip_runtime.h>
#include <hip/hip_bf16.h>

// Problem constants
#define BB 8
#define HH 640
#define WW 640
#define HWN (HH * WW)          // 409600 pixels per batch
#define NUM_INST 16
#define NBLK 64                // blocks per batch
#define NBLK_TOT (NBLK * BB)   // 512 blocks total
#define THREADS 256
#define NV 52                  // per-block partials: 16 s1 | 16 s2 | 16 cnt | pos,neg,or,posCnt

// ws layout: ws[v * NBLK_TOT + g]  (v in [0,52), g = b*NBLK + blockIdx.x)
// Total ws use: 52 * 512 * 4 B = 106496 B. No zero-init required (plain stores).

__device__ __forceinline__ void process_pixel(
    float p1, float p2, float c, float t, int k,
    float* a1, float* a2, float* cf,
    float& accPos, float& accNeg, float& accOr, float& accCnt)
{
    float andp = p1 * p2;
    bool tpos = (t != 0.0f);
    bool cpos = (c != 0.0f);
    // BCE(and_preds, overlap): overlap is exactly 0/1 -> select log argument, one log
    float argA = tpos ? andp : (1.0f - andp);
    float bce_and = -fmaxf(__logf(argA), -100.0f);
    accPos += cpos ? bce_and : 0.0f;
    accNeg += cpos ? 0.0f : bce_and;
    accCnt += c;
    // BCE(max(p1,p2), conf): conf exactly 0/1
    float mx = fmaxf(p1, p2);
    float argO = cpos ? mx : (1.0f - mx);
    accOr -= fmaxf(__logf(argO), -100.0f);
    // instance term
    float ao = tpos ? andp : 0.0f;            // and_preds * overlap
    float d1 = fmaxf(p1, ao) - 1.0f;
    float d2 = fmaxf(p2, ao) - 1.0f;
    float e1 = d1 * d1;
    float e2 = d2 * d2;
    #pragma unroll
    for (int j = 0; j < NUM_INST; ++j) {
        bool m = (k == j);
        a1[j] += m ? e1 : 0.0f;
        a2[j] += m ? e2 : 0.0f;
        cf[j] += m ? 1.0f : 0.0f;
    }
}

__global__ __launch_bounds__(THREADS) void overlap_main_kernel(
    const float* __restrict__ preds, const float* __restrict__ conf,
    const int* __restrict__ inst, const float* __restrict__ overlap,
    float* __restrict__ ws)
{
    const int b   = blockIdx.y;
    const int tid = threadIdx.x;

    const float4* p1v = (const float4*)(preds + (size_t)b * 2 * HWN);
    const float4* p2v = (const float4*)(preds + (size_t)b * 2 * HWN + HWN);
    const float4* cv  = (const float4*)(conf    + (size_t)b * HWN);
    const float4* tv  = (const float4*)(overlap + (size_t)b * HWN);
    const int4*   kv  = (const int4*)(inst      + (size_t)b * HWN);

    float vals[NV];
    #pragma unroll
    for (int v = 0; v < NV; ++v) vals[v] = 0.0f;
    float* a1 = vals;             // [0..15]
    float* a2 = vals + 16;        // [16..31]
    float* cf = vals + 32;        // [32..47]
    float& accPos = vals[48];
    float& accNeg = vals[49];
    float& accOr  = vals[50];
    float& accCnt = vals[51];

    const int nvec   = HWN / 4;
    const int stride = gridDim.x * blockDim.x;
    for (int i = blockIdx.x * blockDim.x + tid; i < nvec; i += stride) {
        float4 A = p1v[i];
        float4 B = p2v[i];
        float4 C = cv[i];
        float4 T = tv[i];
        int4   K = kv[i];
        process_pixel(A.x, B.x, C.x, T.x, K.x, a1, a2, cf, accPos, accNeg, accOr, accCnt);
        process_pixel(A.y, B.y, C.y, T.y, K.y, a1, a2, cf, accPos, accNeg, accOr, accCnt);
        process_pixel(A.z, B.z, C.z, T.z, K.z, a1, a2, cf, accPos, accNeg, accOr, accCnt);
        process_pixel(A.w, B.w, C.w, T.w, K.w, a1, a2, cf, accPos, accNeg, accOr, accCnt);
    }

    // 64-lane butterfly reduction of all 52 partials
    #pragma unroll
    for (int s = 32; s > 0; s >>= 1) {
        #pragma unroll
        for (int v = 0; v < NV; ++v) vals[v] += __shfl_xor(vals[v], s, 64);
    }

    __shared__ float wsum[4][NV];
    const int wave = tid >> 6;
    const int lane = tid & 63;
    if (lane == 0) {
        #pragma unroll
        for (int v = 0; v < NV; ++v) wsum[wave][v] = vals[v];
    }
    __syncthreads();
    if (tid < NV) {
        float s = wsum[0][tid] + wsum[1][tid] + wsum[2][tid] + wsum[3][tid];
        int g = blockIdx.y * NBLK + blockIdx.x;
        ws[tid * NBLK_TOT + g] = s;   // plain store, no atomics
    }
}

__global__ __launch_bounds__(512) void overlap_finalize_kernel(
    const float* __restrict__ ws, float* __restrict__ out)
{
    __shared__ float seg[BB][NV];
    __shared__ float perkey[BB][NUM_INST];
    __shared__ float pres[BB][NUM_INST];
    __shared__ float binst[BB];
    const int t = threadIdx.x;

    if (t < BB * NV) {
        int b = t / NV, v = t % NV;
        const float* p = ws + v * NBLK_TOT + b * NBLK;
        float s = 0.0f;
        #pragma unroll 8
        for (int i = 0; i < NBLK; ++i) s += p[i];
        seg[b][v] = s;
    }
    __syncthreads();

    if (t < BB * NUM_INST) {
        int b = t >> 4, k = t & 15;
        float cnt = seg[b][32 + k];
        bool present = cnt > 0.0f;
        float sc = present ? cnt : 1.0f;
        float d = seg[b][k] / sc - seg[b][16 + k] / sc;
        perkey[b][k] = present ? (1.0f - fabsf(d)) : 0.0f;
        pres[b][k]   = present ? 1.0f : 0.0f;
    }
    __syncthreads();

    if (t < BB) {
        float s = 0.0f, nk = 0.0f;
        for (int k = 0; k < NUM_INST; ++k) { s += perkey[t][k]; nk += pres[t][k]; }
        binst[t] = s / nk;
    }
    __syncthreads();

    if (t == 0) {
        float instLoss = 0.0f, posS = 0.0f, negS = 0.0f, orS = 0.0f, posC = 0.0f;
        for (int b = 0; b < BB; ++b) {
            instLoss += binst[b];
            posS += seg[b][48];
            negS += seg[b][49];
            orS  += seg[b][50];
            posC += seg[b][51];
        }
        instLoss *= (1.0f / (float)BB);
        const float N = (float)BB * (float)HWN;
        float andLoss = posS / posC + negS / (N - posC);
        float orLoss  = orS / N;
        out[0] = 0.5f * andLoss + 0.25f * orLoss + 0.25f * instLoss;
    }
}

extern "C" void kernel_launch(void* const* d_in, const int* in_sizes, int n_in,
                              void* d_out, int out_size, void* d_ws, size_t ws_size,
                              hipStream_t stream) {
    const float* preds   = (const float*)d_in[0];
    const float* conf    = (const float*)d_in[1];
    const int*   inst    = (const int*)d_in[2];
    const float* overlap = (const float*)d_in[3];
    // d_in[4] (inds) is unused by the reference computation.
    float* ws  = (float*)d_ws;
    float* out = (float*)d_out;

    dim3 grid(NBLK, BB);
    overlap_main_kernel<<<grid, THREADS, 0, stream>>>(preds, conf, inst, overlap, ws);
    overlap_finalize_kernel<<<1, 512, 0, stream>>>(ws, out);
}

// Round 3
// 112.511 us; speedup vs baseline: 1.4073x; 1.0209x over previous
//
#include <hip/hip_runtime.h>
#include <hip/hip_bf16.h>

// Problem constants
#define BB 8
#define HH 640
#define WW 640
#define HWN (HH * WW)          // 409600 pixels per batch
#define NUM_INST 16
#define NBLK 128               // blocks per batch
#define NBLK_TOT (NBLK * BB)   // 1024 blocks total
#define THREADS 256
#define NV 36                  // 16 s12-bins | 16 cnt-bins | pos, all, or, posCnt

// ws layout: ws[v * NBLK_TOT + g], g = b*NBLK + blockIdx.x
// Total ws use: 36 * 1024 * 4 B = 147456 B. Plain stores, no zero-init needed.

__device__ __forceinline__ void process_pixel(
    float p1, float p2, float c, float t, int k,
    float* s12, float* cnt,
    float& accPos, float& accAll, float& accOr, float& accCnt)
{
    float andp = p1 * p2;
    bool tpos = (t != 0.0f);
    bool cpos = (c != 0.0f);
    // BCE(and_preds, overlap): overlap is exactly 0/1 -> one log, select the argument
    float argA = tpos ? andp : (1.0f - andp);
    float bce_and = -fmaxf(__logf(argA), -100.0f);
    accAll += bce_and;                        // pos+neg sum; neg recovered in finalize
    accPos += cpos ? bce_and : 0.0f;
    accCnt += c;
    // BCE(max(p1,p2), conf): conf exactly 0/1
    float mx = fmaxf(p1, p2);
    float argO = cpos ? mx : (1.0f - mx);
    accOr -= fmaxf(__logf(argO), -100.0f);
    // instance term: only need e1-e2 per segment since |d1-d2| = |s1-s2|/cnt
    float ao = tpos ? andp : 0.0f;            // and_preds * overlap
    float d1 = fmaxf(p1, ao) - 1.0f;
    float d2 = fmaxf(p2, ao) - 1.0f;
    float e12 = (d1 - d2) * (d1 + d2);        // d1^2 - d2^2
    #pragma unroll
    for (int j = 0; j < NUM_INST; ++j) {
        bool m = (k == j);
        s12[j] += m ? e12  : 0.0f;
        cnt[j] += m ? 1.0f : 0.0f;
    }
}

__global__ __launch_bounds__(THREADS) void overlap_main_kernel(
    const float* __restrict__ preds, const float* __restrict__ conf,
    const int* __restrict__ inst, const float* __restrict__ overlap,
    float* __restrict__ ws)
{
    const int b   = blockIdx.y;
    const int tid = threadIdx.x;

    const float4* p1v = (const float4*)(preds + (size_t)b * 2 * HWN);
    const float4* p2v = (const float4*)(preds + (size_t)b * 2 * HWN + HWN);
    const float4* cv  = (const float4*)(conf    + (size_t)b * HWN);
    const float4* tv  = (const float4*)(overlap + (size_t)b * HWN);
    const int4*   kv  = (const int4*)(inst      + (size_t)b * HWN);

    float vals[NV];
    #pragma unroll
    for (int v = 0; v < NV; ++v) vals[v] = 0.0f;
    float* s12 = vals;            // [0..15]
    float* cnt = vals + 16;       // [16..31]
    float& accPos = vals[32];
    float& accAll = vals[33];
    float& accOr  = vals[34];
    float& accCnt = vals[35];

    const int nvec   = HWN / 4;
    const int stride = gridDim.x * blockDim.x;
    for (int i = blockIdx.x * blockDim.x + tid; i < nvec; i += stride) {
        float4 A = p1v[i];
        float4 B = p2v[i];
        float4 C = cv[i];
        float4 T = tv[i];
        int4   K = kv[i];
        process_pixel(A.x, B.x, C.x, T.x, K.x, s12, cnt, accPos, accAll, accOr, accCnt);
        process_pixel(A.y, B.y, C.y, T.y, K.y, s12, cnt, accPos, accAll, accOr, accCnt);
        process_pixel(A.z, B.z, C.z, T.z, K.z, s12, cnt, accPos, accAll, accOr, accCnt);
        process_pixel(A.w, B.w, C.w, T.w, K.w, s12, cnt, accPos, accAll, accOr, accCnt);
    }

    // 64-lane butterfly reduction of all 36 partials (xor 1,2,4,8 lower to DPP)
    #pragma unroll
    for (int s = 32; s > 0; s >>= 1) {
        #pragma unroll
        for (int v = 0; v < NV; ++v) vals[v] += __shfl_xor(vals[v], s, 64);
    }

    __shared__ float wsum[4][NV];
    const int wave = tid >> 6;
    const int lane = tid & 63;
    if (lane == 0) {
        #pragma unroll
        for (int v = 0; v < NV; ++v) wsum[wave][v] = vals[v];
    }
    __syncthreads();
    if (tid < NV) {
        float s = wsum[0][tid] + wsum[1][tid] + wsum[2][tid] + wsum[3][tid];
        int g = blockIdx.y * NBLK + blockIdx.x;
        ws[tid * NBLK_TOT + g] = s;   // plain store, no atomics
    }
}

__global__ __launch_bounds__(320) void overlap_finalize_kernel(
    const float* __restrict__ ws, float* __restrict__ out)
{
    __shared__ float seg[BB][NV];
    __shared__ float perkey[BB][NUM_INST];
    __shared__ float pres[BB][NUM_INST];
    __shared__ float binst[BB];
    const int t = threadIdx.x;

    if (t < BB * NV) {
        int b = t / NV, v = t % NV;
        const float4* p = (const float4*)(ws + v * NBLK_TOT + b * NBLK);
        float4 s4 = {0.0f, 0.0f, 0.0f, 0.0f};
        #pragma unroll 8
        for (int i = 0; i < NBLK / 4; ++i) {
            float4 q = p[i];
            s4.x += q.x; s4.y += q.y; s4.z += q.z; s4.w += q.w;
        }
        seg[b][v] = (s4.x + s4.y) + (s4.z + s4.w);
    }
    __syncthreads();

    if (t < BB * NUM_INST) {
        int b = t >> 4, k = t & 15;
        float c = seg[b][16 + k];
        bool present = c > 0.0f;
        float sc = present ? c : 1.0f;
        perkey[b][k] = present ? (1.0f - fabsf(seg[b][k]) / sc) : 0.0f;
        pres[b][k]   = present ? 1.0f : 0.0f;
    }
    __syncthreads();

    if (t < BB) {
        float s = 0.0f, nk = 0.0f;
        for (int k = 0; k < NUM_INST; ++k) { s += perkey[t][k]; nk += pres[t][k]; }
        binst[t] = s / nk;
    }
    __syncthreads();

    if (t == 0) {
        float instLoss = 0.0f, posS = 0.0f, allS = 0.0f, orS = 0.0f, posC = 0.0f;
        for (int b = 0; b < BB; ++b) {
            instLoss += binst[b];
            posS += seg[b][32];
            allS += seg[b][33];
            orS  += seg[b][34];
            posC += seg[b][35];
        }
        instLoss *= (1.0f / (float)BB);
        const float N = (float)BB * (float)HWN;
        float negS = allS - posS;
        float andLoss = posS / posC + negS / (N - posC);
        float orLoss  = orS / N;
        out[0] = 0.5f * andLoss + 0.25f * orLoss + 0.25f * instLoss;
    }
}

extern "C" void kernel_launch(void* const* d_in, const int* in_sizes, int n_in,
                              void* d_out, int out_size, void* d_ws, size_t ws_size,
                              hipStream_t stream) {
    const float* preds   = (const float*)d_in[0];
    const float* conf    = (const float*)d_in[1];
    const int*   inst    = (const int*)d_in[2];
    const float* overlap = (const float*)d_in[3];
    // d_in[4] (inds) is unused by the reference computation.
    float* ws  = (float*)d_ws;
    float* out = (float*)d_out;

    dim3 grid(NBLK, BB);
    overlap_main_kernel<<<grid, THREADS, 0, stream>>>(preds, conf, inst, overlap, ws);
    overlap_finalize_kernel<<<1, 320, 0, stream>>>(ws, out);
}